// Round 17
// baseline (66.028 us; speedup 1.0000x reference)
//
#include <hip/hip_runtime.h>
#include <math.h>

#define B_DIM 256
#define M_DIM 256
#define C_DIM 1024
#define C4    256            // C/4 float4 per row
#define UM_OFF (B_DIM * C_DIM)                       // 262144 floats
#define KL_OFF (UM_OFF + B_DIM * M_DIM * C_DIM)      // 67371008 floats
#define SCALE  0.03125f      // 1/sqrt(1024)

__device__ __forceinline__ float dot4(float4 a, float4 b) {
    return a.x*b.x + a.y*b.y + a.z*b.z + a.w*b.w;
}
__device__ __forceinline__ float wsum(float v) {
    #pragma unroll
    for (int off = 32; off; off >>= 1) v += __shfl_xor(v, off, 64);
    return v;
}
__device__ __forceinline__ float wmax(float v) {
    #pragma unroll
    for (int off = 32; off; off >>= 1) v = fmaxf(v, __shfl_xor(v, off, 64));
    return v;
}
__device__ __forceinline__ float4 blend9(float4 v, float4 xr) {
    return make_float4(0.9f*v.x + 0.1f*xr.x, 0.9f*v.y + 0.1f*xr.y,
                       0.9f*v.z + 0.1f*xr.z, 0.9f*v.w + 0.1f*xr.w);
}

// ---------------- K1: stream + free-rider sims (R16 verbatim). 8192 x 256.
__global__ __launch_bounds__(256) void tm_stream(const float* __restrict__ x,
                                                 const float* __restrict__ mem,
                                                 float* __restrict__ out) {
    const int j = blockIdx.x;       // 0..8191
    const int b  = j >> 5;
    const int m0 = (j & 31) << 3;   // 0,8,...,248
    const int t = threadIdx.x;      // column float4 id
    const int lane = t & 63;
    const int wv = t >> 6;          // 0..3

    __shared__ float s_p[8][4];     // [row][wave]

    const float4* src = (const float4*)mem + (m0 << 8) + t;
    float4 r0 = src[0 << 8];
    float4 r1 = src[1 << 8];
    float4 r2 = src[2 << 8];
    float4 r3 = src[3 << 8];
    float4 r4 = src[4 << 8];
    float4 r5 = src[5 << 8];
    float4 r6 = src[6 << 8];
    float4 r7 = src[7 << 8];
    const float4 xv = ((const float4*)(x + (size_t)b * C_DIM))[t];

    // sims partials from already-staged registers
    float p0 = dot4(r0, xv), p1 = dot4(r1, xv), p2 = dot4(r2, xv), p3 = dot4(r3, xv);
    float p4 = dot4(r4, xv), p5 = dot4(r5, xv), p6 = dot4(r6, xv), p7 = dot4(r7, xv);
    p0 = wsum(p0); p1 = wsum(p1); p2 = wsum(p2); p3 = wsum(p3);
    p4 = wsum(p4); p5 = wsum(p5); p6 = wsum(p6); p7 = wsum(p7);
    if (lane == 0) {
        s_p[0][wv] = p0; s_p[1][wv] = p1; s_p[2][wv] = p2; s_p[3][wv] = p3;
        s_p[4][wv] = p4; s_p[5][wv] = p5; s_p[6][wv] = p6; s_p[7][wv] = p7;
    }
    __syncthreads();
    if (t < 8)
        out[(size_t)b * C_DIM + m0 + t] = s_p[t][0] + s_p[t][1] + s_p[t][2] + s_p[t][3];

    // pure store burst (raw rows; blend row rewritten by K2)
    float4* dst = (float4*)(out + UM_OFF) + ((size_t)b << 16) + (m0 << 8) + t;
    dst[0 << 8] = r0;
    dst[1 << 8] = r1;
    dst[2 << 8] = r2;
    dst[3 << 8] = r3;
    dst[4 << 8] = r4;
    dst[5 << 8] = r5;
    dst[6 << 8] = r6;
    dst[7 << 8] = r7;
}

// ---------------- K2: 4-batch finish (R14 prefix structure, standalone).
// 64 blocks x 256 thr. Sims from K1's stash; one mem pass serves 4 batches'
// z via LDS-transposed attn; blend-row write folded into correction loop.
__global__ __launch_bounds__(256) void tm_post(const float* __restrict__ x,
                                               const float* __restrict__ mem,
                                               float* __restrict__ out) {
    const int g = blockIdx.x;          // 0..63
    const int t = threadIdx.x;         // 0..255
    const int lane = t & 63;
    const int wv = t >> 6;             // 0..3
    const int b0 = g << 2;

    __shared__ float4 s_x[4][C4];        // 16 KB
    __shared__ float  s_sims[4][M_DIM];  // 4 KB
    __shared__ float  s_attnT[M_DIM*4];  // 4 KB  [m][j]
    __shared__ float  s_aidx[4];
    __shared__ float  s_dw[4];
    __shared__ int    s_idxv[4];
    __shared__ float4 s_red4[4];

    const float4* mem4 = (const float4*)mem;

    // ---- stage x rows + sims rows (K1's stash in z region of out) ----
    #pragma unroll
    for (int j = 0; j < 4; ++j) {
        s_x[j][t]    = ((const float4*)(x + (size_t)(b0 + j) * C_DIM))[t];
        s_sims[j][t] = out[(size_t)(b0 + j) * C_DIM + t];
    }
    __syncthreads();                                   // barrier 1

    // ---- softmax: wave wv owns batch j = wv entirely ----
    {
        const int j = wv;
        const float v0 = s_sims[j][lane];
        const float v1 = s_sims[j][lane + 64];
        const float v2 = s_sims[j][lane + 128];
        const float v3 = s_sims[j][lane + 192];
        const float4 xa = s_x[j][lane], xb = s_x[j][lane + 64];
        const float4 xc = s_x[j][lane + 128], xd = s_x[j][lane + 192];
        const float n2 = wsum(dot4(xa,xa) + dot4(xb,xb) + dot4(xc,xc) + dot4(xd,xd));

        float av = v0; int am = lane;
        if (v1 > av) { av = v1; am = lane + 64; }
        if (v2 > av) { av = v2; am = lane + 128; }
        if (v3 > av) { av = v3; am = lane + 192; }
        #pragma unroll
        for (int off = 32; off; off >>= 1) {
            float ov = __shfl_xor(av, off, 64);
            int   oi = __shfl_xor(am, off, 64);
            if (ov > av || (ov == av && oi < am)) { av = ov; am = oi; }
        }
        const int idx = am;
        const float fused = 0.9f * av + 0.1f * n2;

        float s0 = ((lane      ) == idx ? fused : v0) * SCALE;
        float s1 = ((lane +  64) == idx ? fused : v1) * SCALE;
        float s2 = ((lane + 128) == idx ? fused : v2) * SCALE;
        float s3 = ((lane + 192) == idx ? fused : v3) * SCALE;
        const float mx = wmax(fmaxf(fmaxf(s0, s1), fmaxf(s2, s3)));
        const float e0 = expf(s0 - mx), e1 = expf(s1 - mx);
        const float e2 = expf(s2 - mx), e3 = expf(s3 - mx);
        const float inv = 1.0f / wsum(e0 + e1 + e2 + e3);
        const float a0 = e0 * inv, a1 = e1 * inv, a2 = e2 * inv, a3 = e3 * inv;

        s_attnT[(lane      ) * 4 + j] = a0;
        s_attnT[(lane +  64) * 4 + j] = a1;
        s_attnT[(lane + 128) * 4 + j] = a2;
        s_attnT[(lane + 192) * 4 + j] = a3;

        float aidx;
        if      (idx <  64) aidx = __shfl(a0, idx,       64);
        else if (idx < 128) aidx = __shfl(a1, idx - 64,  64);
        else if (idx < 192) aidx = __shfl(a2, idx - 128, 64);
        else                aidx = __shfl(a3, idx - 192, 64);

        // dw = ||x - mem[idx]||^2
        const float4* ir = mem4 + (idx << 8);
        float4 q0 = ir[lane], q1 = ir[lane+64], q2 = ir[lane+128], q3 = ir[lane+192];
        float p = 0.f; float4 dq;
        dq = make_float4(xa.x-q0.x, xa.y-q0.y, xa.z-q0.z, xa.w-q0.w); p += dot4(dq,dq);
        dq = make_float4(xb.x-q1.x, xb.y-q1.y, xb.z-q1.z, xb.w-q1.w); p += dot4(dq,dq);
        dq = make_float4(xc.x-q2.x, xc.y-q2.y, xc.z-q2.z, xc.w-q2.w); p += dot4(dq,dq);
        dq = make_float4(xd.x-q3.x, xd.y-q3.y, xd.z-q3.z, xd.w-q3.w); p += dot4(dq,dq);
        const float dwv = wsum(p);

        if (lane == 0) {
            s_idxv[j] = idx;
            s_aidx[j] = aidx * 0.1f;
            s_dw[j]   = dwv;
        }
    }
    __syncthreads();                                   // barrier 2

    // ---- z pass: one mem pass serves 4 batches; thread t owns column t ----
    float4 z0 = make_float4(0,0,0,0), z1 = z0, z2 = z0, z3 = z0;
    const float4* attn4 = (const float4*)s_attnT;
    #pragma unroll 8
    for (int m = 0; m < M_DIM; ++m) {
        float4 v = mem4[(m << 8) + t];
        float4 a = attn4[m];
        z0.x = fmaf(a.x, v.x, z0.x); z0.y = fmaf(a.x, v.y, z0.y);
        z0.z = fmaf(a.x, v.z, z0.z); z0.w = fmaf(a.x, v.w, z0.w);
        z1.x = fmaf(a.y, v.x, z1.x); z1.y = fmaf(a.y, v.y, z1.y);
        z1.z = fmaf(a.y, v.z, z1.z); z1.w = fmaf(a.y, v.w, z1.w);
        z2.x = fmaf(a.z, v.x, z2.x); z2.y = fmaf(a.z, v.y, z2.y);
        z2.z = fmaf(a.z, v.z, z2.z); z2.w = fmaf(a.z, v.w, z2.w);
        z3.x = fmaf(a.w, v.x, z3.x); z3.y = fmaf(a.w, v.y, z3.y);
        z3.z = fmaf(a.w, v.z, z3.z); z3.w = fmaf(a.w, v.w, z3.w);
    }

    // ---- corrections + blend-row writes + dr + z stores ----
    float4 dr4;
    {
        float drp[4];
        float4 zz[4] = { z0, z1, z2, z3 };
        #pragma unroll
        for (int j = 0; j < 4; ++j) {
            const int idxj = s_idxv[j];
            const float aj = s_aidx[j];
            float4 sl = mem4[(idxj << 8) + t];
            float4 xj = s_x[j][t];
            float4 d = make_float4(xj.x - sl.x, xj.y - sl.y, xj.z - sl.z, xj.w - sl.w);
            zz[j].x = fmaf(aj, d.x, zz[j].x);
            zz[j].y = fmaf(aj, d.y, zz[j].y);
            zz[j].z = fmaf(aj, d.z, zz[j].z);
            zz[j].w = fmaf(aj, d.w, zz[j].w);
            float ex = zz[j].x - xj.x, ey = zz[j].y - xj.y;
            float ez = zz[j].z - xj.z, ew = zz[j].w - xj.w;
            drp[j] = ex*ex + ey*ey + ez*ez + ew*ew;
            ((float4*)out)[(size_t)(b0 + j) * C4 + t] = zz[j];   // overwrites stash
            // blend-row rewrite (K1 wrote it raw; kernel boundary orders us)
            ((float4*)(out + UM_OFF))[((size_t)(b0 + j) << 16) + (idxj << 8) + t]
                = blend9(sl, xj);
        }
        dr4 = make_float4(drp[0], drp[1], drp[2], drp[3]);
        #pragma unroll
        for (int off = 32; off; off >>= 1) {
            dr4.x += __shfl_xor(dr4.x, off, 64);
            dr4.y += __shfl_xor(dr4.y, off, 64);
            dr4.z += __shfl_xor(dr4.z, off, 64);
            dr4.w += __shfl_xor(dr4.w, off, 64);
        }
    }
    if (lane == 0) s_red4[wv] = dr4;
    __syncthreads();                                   // barrier 3
    if (t == 0) {
        float4 s = s_red4[0];
        s.x += s_red4[1].x + s_red4[2].x + s_red4[3].x;
        s.y += s_red4[1].y + s_red4[2].y + s_red4[3].y;
        s.z += s_red4[1].z + s_red4[2].z + s_red4[3].z;
        s.w += s_red4[1].w + s_red4[2].w + s_red4[3].w;
        out[KL_OFF + b0 + 0] = 0.5f * (s_dw[0] + s.x);
        out[KL_OFF + b0 + 1] = 0.5f * (s_dw[1] + s.y);
        out[KL_OFF + b0 + 2] = 0.5f * (s_dw[2] + s.z);
        out[KL_OFF + b0 + 3] = 0.5f * (s_dw[3] + s.w);
    }
}

extern "C" void kernel_launch(void* const* d_in, const int* in_sizes, int n_in,
                              void* d_out, int out_size, void* d_ws, size_t ws_size,
                              hipStream_t stream) {
    const float* x   = (const float*)d_in[0];   // input_encoded [B, C]
    const float* mem = (const float*)d_in[1];   // memory_mean  [M, C]
    float* out = (float*)d_out;

    tm_stream<<<dim3(8192), dim3(256), 0, stream>>>(x, mem, out);
    tm_post<<<dim3(64), dim3(256), 0, stream>>>(x, mem, out);
}

// Round 18
// 58.977 us; speedup vs baseline: 1.1195x; 1.1195x over previous
//
#include <hip/hip_runtime.h>
#include <math.h>

#define B_DIM 256
#define M_DIM 256
#define C_DIM 1024
#define C4    256            // C/4 float4 per row
#define UM_OFF (B_DIM * C_DIM)                       // 262144 floats
#define KL_OFF (UM_OFF + B_DIM * M_DIM * C_DIM)      // 67371008 floats
#define SCALE  0.03125f      // 1/sqrt(1024)

__device__ __forceinline__ float dot4(float4 a, float4 b) {
    return a.x*b.x + a.y*b.y + a.z*b.z + a.w*b.w;
}
__device__ __forceinline__ float wsum(float v) {
    #pragma unroll
    for (int off = 32; off; off >>= 1) v += __shfl_xor(v, off, 64);
    return v;
}
__device__ __forceinline__ float wmax(float v) {
    #pragma unroll
    for (int off = 32; off; off >>= 1) v = fmaxf(v, __shfl_xor(v, off, 64));
    return v;
}
__device__ __forceinline__ float4 blend9(float4 v, float4 xr) {
    return make_float4(0.9f*v.x + 0.1f*xr.x, 0.9f*v.y + 0.1f*xr.y,
                       0.9f*v.z + 0.1f*xr.z, 0.9f*v.w + 0.1f*xr.w);
}

// ---------------- K1: stream + free-rider sims (R16 verbatim). 8192 x 256.
__global__ __launch_bounds__(256) void tm_stream(const float* __restrict__ x,
                                                 const float* __restrict__ mem,
                                                 float* __restrict__ out) {
    const int j = blockIdx.x;       // 0..8191
    const int b  = j >> 5;
    const int m0 = (j & 31) << 3;   // 0,8,...,248
    const int t = threadIdx.x;      // column float4 id
    const int lane = t & 63;
    const int wv = t >> 6;          // 0..3

    __shared__ float s_p[8][4];     // [row][wave]

    const float4* src = (const float4*)mem + (m0 << 8) + t;
    float4 r0 = src[0 << 8];
    float4 r1 = src[1 << 8];
    float4 r2 = src[2 << 8];
    float4 r3 = src[3 << 8];
    float4 r4 = src[4 << 8];
    float4 r5 = src[5 << 8];
    float4 r6 = src[6 << 8];
    float4 r7 = src[7 << 8];
    const float4 xv = ((const float4*)(x + (size_t)b * C_DIM))[t];

    float p0 = dot4(r0, xv), p1 = dot4(r1, xv), p2 = dot4(r2, xv), p3 = dot4(r3, xv);
    float p4 = dot4(r4, xv), p5 = dot4(r5, xv), p6 = dot4(r6, xv), p7 = dot4(r7, xv);
    p0 = wsum(p0); p1 = wsum(p1); p2 = wsum(p2); p3 = wsum(p3);
    p4 = wsum(p4); p5 = wsum(p5); p6 = wsum(p6); p7 = wsum(p7);
    if (lane == 0) {
        s_p[0][wv] = p0; s_p[1][wv] = p1; s_p[2][wv] = p2; s_p[3][wv] = p3;
        s_p[4][wv] = p4; s_p[5][wv] = p5; s_p[6][wv] = p6; s_p[7][wv] = p7;
    }
    __syncthreads();
    if (t < 8)
        out[(size_t)b * C_DIM + m0 + t] = s_p[t][0] + s_p[t][1] + s_p[t][2] + s_p[t][3];

    float4* dst = (float4*)(out + UM_OFF) + ((size_t)b << 16) + (m0 << 8) + t;
    dst[0 << 8] = r0;
    dst[1 << 8] = r1;
    dst[2 << 8] = r2;
    dst[3 << 8] = r3;
    dst[4 << 8] = r4;
    dst[5 << 8] = r5;
    dst[6 << 8] = r6;
    dst[7 << 8] = r7;
}

// ---------------- K2: softmax + partial-z. 256 blocks x 256 thr.
// Block (gg,qq): batches b0..b0+3 over m-quarter qq (64 rows, 256 KB read).
// Wave j owns batch b0+j's softmax (sims from K1 stash). Partial z written to
// um[b][qq] row (scratch; K3 restores). idx/aidx/dw -> ws.
__global__ __launch_bounds__(256) void tm_mid(const float* __restrict__ x,
                                              const float* __restrict__ mem,
                                              float* __restrict__ out,
                                              float* __restrict__ ws) {
    const int blk = blockIdx.x;     // 0..255
    const int gg = blk >> 2;
    const int qq = blk & 3;
    const int b0 = gg << 2;
    const int t = threadIdx.x;
    const int lane = t & 63;
    const int j = t >> 6;           // wave = batch offset
    const int b = b0 + j;

    __shared__ float s_attnT[64][4];   // [local m][batch j]

    const float4* mem4 = (const float4*)mem;

    // ---- per-wave softmax for batch b (sims from stash in z region) ----
    const float* simsrow = out + (size_t)b * C_DIM;
    const float v0 = simsrow[lane];
    const float v1 = simsrow[lane + 64];
    const float v2 = simsrow[lane + 128];
    const float v3 = simsrow[lane + 192];
    const float4* x4 = (const float4*)(x + (size_t)b * C_DIM);
    const float4 xa = x4[lane], xb = x4[lane + 64];
    const float4 xc = x4[lane + 128], xd = x4[lane + 192];
    const float n2 = wsum(dot4(xa,xa) + dot4(xb,xb) + dot4(xc,xc) + dot4(xd,xd));

    // argmax, first-max tie-break (like np.argmax)
    float av = v0; int am = lane;
    if (v1 > av) { av = v1; am = lane + 64; }
    if (v2 > av) { av = v2; am = lane + 128; }
    if (v3 > av) { av = v3; am = lane + 192; }
    #pragma unroll
    for (int off = 32; off; off >>= 1) {
        float ov = __shfl_xor(av, off, 64);
        int   oi = __shfl_xor(am, off, 64);
        if (ov > av || (ov == av && oi < am)) { av = ov; am = oi; }
    }
    const int idx = am;
    const float fused = 0.9f * av + 0.1f * n2;

    float s0 = ((lane      ) == idx ? fused : v0) * SCALE;
    float s1 = ((lane +  64) == idx ? fused : v1) * SCALE;
    float s2 = ((lane + 128) == idx ? fused : v2) * SCALE;
    float s3 = ((lane + 192) == idx ? fused : v3) * SCALE;
    const float mx = wmax(fmaxf(fmaxf(s0, s1), fmaxf(s2, s3)));
    const float e0 = expf(s0 - mx), e1 = expf(s1 - mx);
    const float e2 = expf(s2 - mx), e3 = expf(s3 - mx);
    const float inv = 1.0f / wsum(e0 + e1 + e2 + e3);
    const float a0 = e0 * inv, a1 = e1 * inv, a2 = e2 * inv, a3 = e3 * inv;

    // this quarter's attn value: m = qq*64 + lane
    const float aq = (qq == 0) ? a0 : (qq == 1) ? a1 : (qq == 2) ? a2 : a3;
    s_attnT[lane][j] = aq;

    // idx/aidx/dw published once (qq==0 block)
    if (qq == 0) {
        float aidx;
        if      (idx <  64) aidx = __shfl(a0, idx,       64);
        else if (idx < 128) aidx = __shfl(a1, idx - 64,  64);
        else if (idx < 192) aidx = __shfl(a2, idx - 128, 64);
        else                aidx = __shfl(a3, idx - 192, 64);

        const float4* ir = mem4 + (idx << 8);
        float4 q0 = ir[lane], q1 = ir[lane+64], q2 = ir[lane+128], q3 = ir[lane+192];
        float p = 0.f; float4 dq;
        dq = make_float4(xa.x-q0.x, xa.y-q0.y, xa.z-q0.z, xa.w-q0.w); p += dot4(dq,dq);
        dq = make_float4(xb.x-q1.x, xb.y-q1.y, xb.z-q1.z, xb.w-q1.w); p += dot4(dq,dq);
        dq = make_float4(xc.x-q2.x, xc.y-q2.y, xc.z-q2.z, xc.w-q2.w); p += dot4(dq,dq);
        dq = make_float4(xd.x-q3.x, xd.y-q3.y, xd.z-q3.z, xd.w-q3.w); p += dot4(dq,dq);
        const float dwv = wsum(p);

        if (lane == 0) {
            ((int*)ws)[b]  = idx;
            ws[256 + b] = aidx * 0.1f;
            ws[512 + b] = dwv;
        }
    }
    __syncthreads();

    // ---- partial z over this quarter: thread t owns column t ----
    float4 z0 = make_float4(0,0,0,0), z1 = z0, z2 = z0, z3 = z0;
    const float4* src = mem4 + ((qq << 6) << 8) + t;
    const float4* attn4 = (const float4*)s_attnT;
    #pragma unroll 8
    for (int i = 0; i < 64; ++i) {
        float4 v = src[i << 8];
        float4 a = attn4[i];
        z0.x = fmaf(a.x, v.x, z0.x); z0.y = fmaf(a.x, v.y, z0.y);
        z0.z = fmaf(a.x, v.z, z0.z); z0.w = fmaf(a.x, v.w, z0.w);
        z1.x = fmaf(a.y, v.x, z1.x); z1.y = fmaf(a.y, v.y, z1.y);
        z1.z = fmaf(a.y, v.z, z1.z); z1.w = fmaf(a.y, v.w, z1.w);
        z2.x = fmaf(a.z, v.x, z2.x); z2.y = fmaf(a.z, v.y, z2.y);
        z2.z = fmaf(a.z, v.z, z2.z); z2.w = fmaf(a.z, v.w, z2.w);
        z3.x = fmaf(a.w, v.x, z3.x); z3.y = fmaf(a.w, v.y, z3.y);
        z3.z = fmaf(a.w, v.z, z3.z); z3.w = fmaf(a.w, v.w, z3.w);
    }
    // partial z for batch b0+jj -> scratch row um[b0+jj][qq]
    float4* umb = (float4*)(out + UM_OFF);
    umb[((size_t)(b0 + 0) << 16) + (qq << 8) + t] = z0;
    umb[((size_t)(b0 + 1) << 16) + (qq << 8) + t] = z1;
    umb[((size_t)(b0 + 2) << 16) + (qq << 8) + t] = z2;
    umb[((size_t)(b0 + 3) << 16) + (qq << 8) + t] = z3;
}

// ---------------- K3: combine + kl + restore scratch rows + blend row.
// 256 blocks x 256 thr, one per batch.
__global__ __launch_bounds__(256) void tm_fin(const float* __restrict__ x,
                                              const float* __restrict__ mem,
                                              float* __restrict__ out,
                                              const float* __restrict__ ws) {
    const int b = blockIdx.x;
    const int t = threadIdx.x;
    const int lane = t & 63;
    const int wv = t >> 6;
    __shared__ float s_w[4];

    const int   idx  = ((const int*)ws)[b];
    const float aidx = ws[256 + b];
    const float dw   = ws[512 + b];

    const float4* mem4 = (const float4*)mem;
    float4* um = (float4*)(out + UM_OFF) + ((size_t)b << 16);

    float4 p0 = um[(0 << 8) + t];
    float4 p1 = um[(1 << 8) + t];
    float4 p2 = um[(2 << 8) + t];
    float4 p3 = um[(3 << 8) + t];
    const float4 xv = ((const float4*)(x + (size_t)b * C_DIM))[t];
    float4 sl = mem4[(idx << 8) + t];

    float4 d = make_float4(xv.x - sl.x, xv.y - sl.y, xv.z - sl.z, xv.w - sl.w);
    float4 z;
    z.x = p0.x + p1.x + p2.x + p3.x + aidx * d.x;
    z.y = p0.y + p1.y + p2.y + p3.y + aidx * d.y;
    z.z = p0.z + p1.z + p2.z + p3.z + aidx * d.z;
    z.w = p0.w + p1.w + p2.w + p3.w + aidx * d.w;

    float ex = z.x - xv.x, ey = z.y - xv.y, ez = z.z - xv.z, ew = z.w - xv.w;
    float drp = ex*ex + ey*ey + ez*ez + ew*ew;

    ((float4*)out)[(size_t)b * C4 + t] = z;     // overwrites sims stash

    // restore scratch rows 0..3 (blend if idx there)
    #pragma unroll
    for (int r = 0; r < 4; ++r) {
        float4 v = mem4[(r << 8) + t];
        if (idx == r) v = blend9(v, xv);
        um[(r << 8) + t] = v;
    }
    if (idx >= 4) um[(idx << 8) + t] = blend9(sl, xv);

    const float s = wsum(drp);
    if (lane == 0) s_w[wv] = s;
    __syncthreads();
    if (t == 0)
        out[KL_OFF + b] = 0.5f * (dw + s_w[0] + s_w[1] + s_w[2] + s_w[3]);
}

extern "C" void kernel_launch(void* const* d_in, const int* in_sizes, int n_in,
                              void* d_out, int out_size, void* d_ws, size_t ws_size,
                              hipStream_t stream) {
    const float* x   = (const float*)d_in[0];   // input_encoded [B, C]
    const float* mem = (const float*)d_in[1];   // memory_mean  [M, C]
    float* out = (float*)d_out;
    float* ws  = (float*)d_ws;

    tm_stream<<<dim3(8192), dim3(256), 0, stream>>>(x, mem, out);
    tm_mid<<<dim3(256), dim3(256), 0, stream>>>(x, mem, out, ws);
    tm_fin<<<dim3(256), dim3(256), 0, stream>>>(x, mem, out, ws);
}